// Round 5
// baseline (220025.366 us; speedup 1.0000x reference)
//
#include <hip/hip_runtime.h>
#include <hip/hip_fp16.h>
#include <stdint.h>
#include <string.h>

#define RES      8192
#define IN_DIM   64
#define DYN      1000
#define TOT      2000

#define BLOCKS   256         // 1 block/CU
#define TPB      1024        // 16 waves/block
#define WAVES    16
#define ROWS_PB  32          // rows per block (2 per wave)
#define RPIN     5           // iters pinned in registers (cols 0..2559)
#define LPIN     3           // iters pinned in LDS      (cols 2560..4095)
// iters 8..15 stream from global (cols 4096..8191) -> 50% of W_h traffic cut

// Output layout (floats):
//   prediction          [     0 ..  63999]
//   target              [ 64000 .. 127999]  copy of input[1000:2000]
//   prediction_augment  [128000 .. 255999]
//   target_augment      [256000 .. 383999]  copy of input
//
// ws layout (float indices). Sync lines padded to 128 B. ALL cross-block
// traffic uses relaxed agent-scope atomics (cache-bypass, coherence-point
// served) -> no fences, no L2 invalidates anywhere.  (Round-0 proven layout.)
#define WS_H0     0              // h buffer 0 [8192]
#define WS_H1     8192           // h buffer 1 [8192]
#define WS_OUT    16384          // outbuf [64]
#define WS_DONE   16448          // 64 producer-done slots x 32
#define WS_FLAG   18496          // 32 flag copies x 32
#define WS_GEN    19520          // 32 gen copies x 32
#define WS_SLOT   20544          // 512 arrival slots x 32 (256 used)
#define WS_TOTAL  36928          // floats to zero
#define WS_WH16   40960          // fp16 W_h starts here (float index; 16-B aligned)

__global__ void copy_targets(const float* __restrict__ input, float* __restrict__ out) {
    int i = blockIdx.x * blockDim.x + threadIdx.x;
    if (i < 64000)  out[64000 + i]  = input[64000 + i];   // target
    if (i < 128000) out[256000 + i] = input[i];           // target_augment
}

// fp32 -> fp16 conversion of W_h (67.1M elems). ~384 MiB of traffic, ~75 us.
__global__ void convert_wh(const float* __restrict__ W_h, __half2* __restrict__ w16) {
    const float4* src = (const float4*)W_h;
    const int stride = gridDim.x * blockDim.x;
    for (int j = blockIdx.x * blockDim.x + threadIdx.x;
         j < RES * RES / 4; j += stride) {
        float4 v = src[j];
        w16[2 * j]     = __floats2half2_rn(v.x, v.y);
        w16[2 * j + 1] = __floats2half2_rn(v.z, v.w);
    }
}

__device__ __forceinline__ unsigned ld_u32(const unsigned* p) {
    return __hip_atomic_load(p, __ATOMIC_RELAXED, __HIP_MEMORY_SCOPE_AGENT);
}
__device__ __forceinline__ void st_u32(unsigned* p, unsigned v) {
    __hip_atomic_store(p, v, __ATOMIC_RELAXED, __HIP_MEMORY_SCOPE_AGENT);
}
__device__ __forceinline__ float ld_f32(const float* p) {
    return __hip_atomic_load(p, __ATOMIC_RELAXED, __HIP_MEMORY_SCOPE_AGENT);
}
__device__ __forceinline__ void st_f32(float* p, float v) {
    __hip_atomic_store(p, v, __ATOMIC_RELAXED, __HIP_MEMORY_SCOPE_AGENT);
}
__device__ __forceinline__ void st_u64(uint64_t* p, uint64_t v) {
    __hip_atomic_store(p, v, __ATOMIC_RELAXED, __HIP_MEMORY_SCOPE_AGENT);
}
__device__ __forceinline__ uint64_t ld_u64(const uint64_t* p) {
    return __hip_atomic_load(p, __ATOMIC_RELAXED, __HIP_MEMORY_SCOPE_AGENT);
}
__device__ __forceinline__ float2 h2f2(unsigned u) {
    __half2 h;
    *reinterpret_cast<unsigned*>(&h) = u;
    return __half22float2(h);
}

template <bool FP16>
__global__ __launch_bounds__(TPB, 4) void esn_kernel(
    const float* __restrict__ input,   // 2000 x 64
    const float* __restrict__ W_in,    // 8192 x 64
    const float* __restrict__ W_h,     // 8192 x 8192 (fp32, used when !FP16)
    const float* __restrict__ W_out,   // 64 x 8192
    float* __restrict__ out,
    float* __restrict__ ws)
{
    __shared__ __align__(16) float h_lds[RES];
    __shared__ float xbuf[IN_DIM];
    // LDS-pinned W_h slice: per wave, 2 rows x LPIN iters x 64 lanes x 16 B.
    // Wave-private -> no __syncthreads needed around it.  96 KiB.
    __shared__ uint4 wpin[WAVES][2][LPIN][64];

    float*    hbuf0  = ws + WS_H0;
    float*    hbuf1  = ws + WS_H1;
    float*    outbuf = ws + WS_OUT;
    unsigned* done   = (unsigned*)(ws + WS_DONE);
    unsigned* flag   = (unsigned*)(ws + WS_FLAG);
    unsigned* gen    = (unsigned*)(ws + WS_GEN);
    unsigned* slot   = (unsigned*)(ws + WS_SLOT);
    const __half2* wh16 = (const __half2*)(ws + WS_WH16);

    float* pred    = out;            // prediction
    float* aug_out = out + 128000;   // prediction_augment

    const int tid  = threadIdx.x;
    const int lane = tid & 63;
    const int wid  = tid >> 6;
    const int bid  = blockIdx.x;
    const int r0   = bid * ROWS_PB + wid * 2;     // this wave's W_h row pair

    // constant per-thread operands, hoisted out of the time loop
    const float w_in0 = W_in[(size_t)r0 * IN_DIM + lane];
    const float w_in1 = W_in[(size_t)(r0 + 1) * IN_DIM + lane];

    const uint4* wp0u = (const uint4*)(wh16 + (size_t)r0 * (RES / 2));
    const uint4* wp1u = wp0u + (RES / 8);         // 1024 uint4 per row

    // ---- register-pinned W_h slice: iters 0..RPIN-1, 2 rows, 40 VGPRs ----
    uint4 rp0[RPIN], rp1[RPIN];
    if (FP16) {
        #pragma unroll
        for (int d = 0; d < RPIN; ++d) {
            rp0[d] = wp0u[lane + 64 * d];
            rp1[d] = wp1u[lane + 64 * d];
        }
        // ---- LDS-pinned slice: iters RPIN..RPIN+LPIN-1 ----
        #pragma unroll
        for (int it = 0; it < LPIN; ++it) {
            wpin[wid][0][it][lane] = wp0u[lane + 64 * (RPIN + it)];
            wpin[wid][1][it][lane] = wp1u[lane + 64 * (RPIN + it)];
        }
    }

    for (int t = 0; t < TOT; ++t) {
        const float* hcur = (t & 1) ? hbuf1 : hbuf0;
        float*       hnxt = (t & 1) ? hbuf0 : hbuf1;

        // ---- stage h_t into LDS via cache-bypass loads (always-fresh) ----
        {
            const uint64_t* src = (const uint64_t*)hcur;
            uint64_t*       dst = (uint64_t*)h_lds;
            #pragma unroll
            for (int i = 0; i < RES / 2 / TPB; ++i)        // 4 iters
                dst[tid + i * TPB] = ld_u64(src + tid + i * TPB);
        }
        __syncthreads();

        // ---- producers: out_t[j] = W_out[j] @ aug(h_t), wave 1 of blocks 0..63 ----
        if (wid == 1 && bid < 64 && t >= 1) {
            const int j = bid;
            const float* wrow = W_out + (size_t)j * RES;
            float acc = 0.f;
            #pragma unroll 8
            for (int i = 0; i < RES / 256; ++i) {
                const int k = (lane << 2) + (i << 8);
                float4 w = *(const float4*)(wrow + k);
                float4 h = *(const float4*)(h_lds + k);
                // aug: even index -> h*h, odd -> h (k is a multiple of 4)
                acc += w.x * h.x * h.x + w.y * h.y + w.z * h.z * h.z + w.w * h.w;
            }
            #pragma unroll
            for (int off = 32; off; off >>= 1) acc += __shfl_xor(acc, off, 64);
            if (lane == 0) {
                if (t <= DYN)  aug_out[(size_t)(t - 1) * 64 + j] = acc;  // warm_up[t-1]
                if (t >= DYN) {
                    pred[(size_t)(t - DYN) * 64 + j] = acc;              // prediction
                    aug_out[(size_t)t * 64 + j]      = acc;              // aug[t]
                    st_f32(outbuf + j, acc);                             // fed back
                    __builtin_amdgcn_s_waitcnt(0);      // outbuf visible before done
                    st_u32(done + j * 32, (unsigned)(t - DYN + 1));
                }
            }
        }

        // ---- aggregator: wave 0 of block 64 collects done slots, fans flag out ----
        if (wid == 0 && bid == 64 && t >= DYN && t < TOT - 1) {
            const unsigned p = (unsigned)(t - DYN + 1);
            for (;;) {
                unsigned v = ld_u32(done + lane * 32);    // 64 distinct lines
                if (__all((int)(v >= p))) break;
                __builtin_amdgcn_s_sleep(2);
            }
            __builtin_amdgcn_s_waitcnt(0);
            if (lane < 32) st_u32(flag + lane * 32, p);
        }

        if (t == TOT - 1) break;   // last h-update is never consumed

        // ---- h_{t+1}[r0..r0+1] = tanh(W_in @ x_t + W_h @ h_t), 2 rows/wave.
        //      Source mux per iter: global (8..15) -> LDS pin (5..7) ->
        //      register pin (0..4). Globals first so their latency hides
        //      under the pinned FMAs. ----
        {
            float a00 = 0.f, a01 = 0.f, a02 = 0.f, a03 = 0.f;
            float a10 = 0.f, a11 = 0.f, a12 = 0.f, a13 = 0.f;
            if (FP16) {
                const float4* hp = (const float4*)(h_lds + 8 * lane);
                #define FMA2(T0, T1, I) do {                                   \
                    const float4 hA = hp[128 * (I)];                           \
                    const float4 hB = hp[128 * (I) + 1];                       \
                    float2 f;                                                  \
                    f = h2f2((T0).x); a00 += f.x * hA.x; a01 += f.y * hA.y;    \
                    f = h2f2((T0).y); a02 += f.x * hA.z; a03 += f.y * hA.w;    \
                    f = h2f2((T0).z); a00 += f.x * hB.x; a01 += f.y * hB.y;    \
                    f = h2f2((T0).w); a02 += f.x * hB.z; a03 += f.y * hB.w;    \
                    f = h2f2((T1).x); a10 += f.x * hA.x; a11 += f.y * hA.y;    \
                    f = h2f2((T1).y); a12 += f.x * hA.z; a13 += f.y * hA.w;    \
                    f = h2f2((T1).z); a10 += f.x * hB.x; a11 += f.y * hB.y;    \
                    f = h2f2((T1).w); a12 += f.x * hB.z; a13 += f.y * hB.w;    \
                } while (0)

                // global iters (streamed; explicit dwordx4)
                #pragma unroll
                for (int i = RPIN + LPIN; i < 16; ++i) {
                    const uint4 g0 = wp0u[lane + 64 * i];
                    const uint4 g1 = wp1u[lane + 64 * i];
                    FMA2(g0, g1, i);
                }
                // LDS-pinned iters
                #pragma unroll
                for (int it = 0; it < LPIN; ++it) {
                    const uint4 l0 = wpin[wid][0][it][lane];
                    const uint4 l1 = wpin[wid][1][it][lane];
                    FMA2(l0, l1, RPIN + it);
                }
                // register-pinned iters
                #pragma unroll
                for (int d = 0; d < RPIN; ++d) {
                    FMA2(rp0[d], rp1[d], d);
                }
                #undef FMA2
            } else {
                const float* wrowA = W_h + (size_t)r0 * RES;
                const float* wrowB = wrowA + RES;
                #pragma unroll 8
                for (int i = 0; i < RES / 256; ++i) {
                    const int k = (lane << 2) + (i << 8);
                    float4 w0 = *(const float4*)(wrowA + k);
                    float4 w1 = *(const float4*)(wrowB + k);
                    float4 h = *(const float4*)(h_lds + k);
                    a00 += w0.x * h.x; a01 += w0.y * h.y;
                    a02 += w0.z * h.z; a03 += w0.w * h.w;
                    a10 += w1.x * h.x; a11 += w1.y * h.y;
                    a12 += w1.z * h.z; a13 += w1.w * h.w;
                }
            }
            float acc0 = (a00 + a02) + (a01 + a03);
            float acc1 = (a10 + a12) + (a11 + a13);

            // x only needed now: warm -> input row; pred -> wait for flag
            // (overlapped with the whole W_h row-pair load above), thread 0 polls.
            float x_l;
            if (t < DYN) {
                x_l = input[(size_t)t * IN_DIM + lane];
            } else {
                const unsigned p = (unsigned)(t - DYN + 1);
                __syncthreads();
                if (tid == 0) {
                    while (ld_u32(flag + (bid & 31) * 32) < p)
                        __builtin_amdgcn_s_sleep(2);
                }
                __syncthreads();
                if (tid < IN_DIM) xbuf[tid] = ld_f32(outbuf + tid);
                __syncthreads();
                x_l = xbuf[lane];
            }
            acc0 += w_in0 * x_l;
            acc1 += w_in1 * x_l;

            #pragma unroll
            for (int off = 32; off; off >>= 1) {
                acc0 += __shfl_xor(acc0, off, 64);
                acc1 += __shfl_xor(acc1, off, 64);
            }
            if (lane == 0) {
                float2 hv;
                hv.x = tanhf(acc0);
                hv.y = tanhf(acc1);
                uint64_t u;
                memcpy(&u, &hv, 8);
                st_u64((uint64_t*)(hnxt + r0), u);   // r0 even -> 8-B aligned
            }
        }

        // ---- grid barrier: drain own stores, per-block slot store (no RMW),
        //      block 0 scans 256 distinct lines, fans gen out to 32 copies ----
        __builtin_amdgcn_s_waitcnt(0);
        __syncthreads();
        const unsigned e = (unsigned)(t + 1);
        if (tid == 0) st_u32(slot + bid * 32, e);
        if (bid == 0) {
            unsigned v = e;
            for (;;) {
                if (tid < BLOCKS) v = ld_u32(slot + tid * 32);
                if (__syncthreads_and(tid >= BLOCKS || v >= e)) break;
                __builtin_amdgcn_s_sleep(2);
            }
            if (tid < 32) st_u32(gen + tid * 32, e);
        } else {
            if (tid == 0) {
                while (ld_u32(gen + (bid & 31) * 32) < e)
                    __builtin_amdgcn_s_sleep(4);
            }
            __syncthreads();
        }
    }
}

extern "C" void kernel_launch(void* const* d_in, const int* in_sizes, int n_in,
                              void* d_out, int out_size, void* d_ws, size_t ws_size,
                              hipStream_t stream) {
    const float* input = (const float*)d_in[0];
    const float* W_in  = (const float*)d_in[1];
    const float* W_h   = (const float*)d_in[2];
    const float* W_out = (const float*)d_in[3];
    float* out = (float*)d_out;
    float* ws  = (float*)d_ws;

    // sync area + h buffers must start at zero (ws is poisoned 0xAA each call)
    hipMemsetAsync(d_ws, 0, WS_TOTAL * sizeof(float), stream);

    copy_targets<<<dim3((128000 + 255) / 256), dim3(256), 0, stream>>>(input, out);

    const size_t need = (size_t)WS_WH16 * sizeof(float)
                      + (size_t)RES * RES * sizeof(__half);
    if (ws_size >= need) {
        // fp16 W_h (128 MiB -> Infinity-Cache-resident; 50% also on-CU pinned)
        convert_wh<<<dim3(2048), dim3(1024), 0, stream>>>(
            W_h, (__half2*)(ws + WS_WH16));
        esn_kernel<true><<<dim3(BLOCKS), dim3(TPB), 0, stream>>>(
            input, W_in, W_h, W_out, out, ws);
    } else {
        // fallback: fp32 path
        esn_kernel<false><<<dim3(BLOCKS), dim3(TPB), 0, stream>>>(
            input, W_in, W_h, W_out, out, ws);
    }
}